// Round 13
// baseline (57.422 us; speedup 1.0000x reference)
//
#include <hip/hip_runtime.h>

#define EPSLN 1e-5f
#define KMINC 9
#define NW    5          // waves per item-block in k_rest; wave = one 16-row M-tile

typedef _Float16 h2 __attribute__((ext_vector_type(2)));
typedef _Float16 h4 __attribute__((ext_vector_type(4)));
typedef _Float16 h8 __attribute__((ext_vector_type(8)));
typedef float f32x4 __attribute__((ext_vector_type(4)));

__device__ __forceinline__ h2 mk2(float a, float b){
  h2 v; v[0]=(_Float16)a; v[1]=(_Float16)b; return v;
}
__device__ __forceinline__ unsigned h2bits(h2 v){
  union { h2 h; unsigned u; } c; c.h = v; return c.u;
}
__device__ __forceinline__ h8 asH8(uint4 u){
  union { uint4 u; h8 h; } c; c.u = u; return c.h;
}

__device__ __forceinline__ float wred64(float v){
  #pragma unroll
  for (int m=1;m<64;m<<=1) v += __shfl_xor(v,m,64);
  return v;
}
__device__ __forceinline__ float wred32(float v){
  #pragma unroll
  for (int m=1;m<32;m<<=1) v += __shfl_xor(v,m,64);
  return v;
}

// ws word-offsets (only node + m0b cross kernels now)
#define WS_NODE   0            // 16384 f32
#define WS_M0B    16384        // 8192 f32

// ---------------- Kernel N: msa-LN -> attention -> node -> m0b ----------------
// grid = B*L (512), block = 512 (8 waves)
__global__ __launch_bounds__(512) void k_node(
    const float* __restrict__ msa, const float* __restrict__ seq1hot,
    const float* __restrict__ g_msa, const float* __restrict__ b_msa,
    const float* __restrict__ Wq, const float* __restrict__ bq,
    const float* __restrict__ Wk, const float* __restrict__ bk,
    const float* __restrict__ Wx, const float* __restrict__ bx,
    const float* __restrict__ g_node, const float* __restrict__ b_node,
    const float* __restrict__ W0, const float* __restrict__ b0,
    float* __restrict__ node, float* __restrict__ m0bG)
{
  const int bid = blockIdx.x;          // b*256 + l
  const int b = bid >> 8;
  const int tid = threadIdx.x;
  const int w = tid >> 6, lane = tid & 63;   // 8 waves

  __shared__ float mn[32][64];
  __shared__ float qS[64];
  __shared__ float scS[32];
  __shared__ float redS[8][64];
  __shared__ float ssumS[8];
  __shared__ float nodeS[32];

  const float gm = g_msa[lane], bm = b_msa[lane];
  for (int nn=w; nn<32; nn+=8){
    float x = msa[(size_t)(((b*32+nn)<<8)+(bid&255))*64 + lane];
    float s = wred64(x), s2 = wred64(x*x);
    float mu = s*(1.f/64.f);
    float var = s2*(1.f/64.f) - mu*mu;
    mn[nn][lane] = (x-mu)*rsqrtf(var+EPSLN)*gm + bm;
  }
  __syncthreads();
  {
    float p = (w==0)? bq[lane] : 0.f;
    for (int d=w*8; d<w*8+8; d++) p += mn[0][d]*Wq[d*64+lane];
    redS[w][lane] = p;
  }
  __syncthreads();
  if (w==0){
    float q = 0.f;
    #pragma unroll
    for (int k=0;k<8;k++) q += redS[k][lane];
    qS[lane] = q*0.125f;               // 1/sqrt(64)
  }
  __syncthreads();
  {
    float p = 0.f;
    for (int e=w*8; e<w*8+8; e++) p += Wk[lane*64+e]*qS[e];
    redS[w][lane] = p;
  }
  __syncthreads();
  float qk = 0.f;
  #pragma unroll
  for (int k=0;k<8;k++) qk += redS[k][lane];
  const float qb_ = wred64(qS[lane]*bk[lane]);
  for (int nn=w*4; nn<w*4+4; nn++){
    float p = wred64(mn[nn][lane]*qk);
    if (lane==0) scS[nn] = p + qb_;
  }
  __syncthreads();
  float mx = -1e30f;
  for (int nn=0; nn<32; nn++) mx = fmaxf(mx, scS[nn]);
  float ps=0.f, pm=0.f;
  for (int nn=w*4; nn<w*4+4; nn++){
    float e = expf(scS[nn]-mx);
    ps += e; pm += e*mn[nn][lane];
  }
  redS[w][lane] = pm;
  if (lane==0) ssumS[w] = ps;
  __syncthreads();
  if (w==0){
    float ssum = 0.f, acc = 0.f;
    #pragma unroll
    for (int k=0;k<8;k++){ ssum += ssumS[k]; acc += redS[k][lane]; }
    qS[lane] = acc / ssum;
  }
  __syncthreads();
  if (tid<32){
    float acc = bx[tid];
    for (int k=0;k<64;k++) acc += qS[k]*Wx[k*32+tid];
    const float* s1 = &seq1hot[bid*21];
    for (int k=0;k<21;k++) acc += s1[k]*Wx[(64+k)*32+tid];
    float s = wred32(acc), s2 = wred32(acc*acc);
    float mu = s*(1.f/32.f), var = s2*(1.f/32.f)-mu*mu;
    float v = (acc-mu)*rsqrtf(var+EPSLN)*g_node[tid] + b_node[tid];
    node[bid*32+tid] = v;
    nodeS[tid] = v;
  }
  __syncthreads();
  if (tid<16){
    float acc = b0[tid];
    for (int k=0;k<32;k++) acc += nodeS[k]*W0[(32+k)*16+tid];
    m0bG[bid*16+tid] = acc;
  }
}

// ---------------- Kernel R: per-item block — topk + gather + fold + MFMA chain ----------------
// grid = B*L (512), block = 320 (5 waves). No cross-kernel data except node/m0b.
// Order: topk(in-LDS jlist) -> issue 8 pair loads/wave upfront -> weight fold (hides
// gather latency) -> stage/LN1 -> GEMM1..4 (r12-verified MFMA chain) -> outputs.
__global__ __launch_bounds__(320, 3) void k_rest(
    const float* __restrict__ pair, const float* __restrict__ xyz,
    const int* __restrict__ idxp, const int* __restrict__ topk,
    const float* __restrict__ g_pair, const float* __restrict__ b_pair,
    const float* __restrict__ We, const float* __restrict__ be,
    const float* __restrict__ g_edge, const float* __restrict__ b_edge,
    const float* __restrict__ Wa, const float* __restrict__ ba,
    const float* __restrict__ W0, const float* __restrict__ b0,
    const float* __restrict__ Wc1, const float* __restrict__ Wc2,
    const float* __restrict__ node, const float* __restrict__ m0bG,
    float* __restrict__ out)
{
  const int tid = threadIdx.x;
  const int w   = tid >> 6;         // wave 0..4
  const int L   = tid & 63;         // lane
  const int h   = L >> 5;           // half
  const int l32 = L & 31;           // lane-in-half
  const int q   = L >> 4;           // k-chunk / row-subgroup 0..3
  const int cl  = L & 15;           // col (B/D) or row (A)

  __shared__ alignas(16) unsigned char GwB[8192];
  __shared__ alignas(16) unsigned char GwaB[2048];
  __shared__ alignas(16) unsigned char W0aB[1024];
  __shared__ alignas(16) unsigned char W0cB[1024];
  __shared__ alignas(16) unsigned char WcB[1024];
  __shared__ float waDS[32], gwS[32], bwS[32], gwaS[32], bwaS[32];
  __shared__ float m0bS[16];
  __shared__ float wfS[6][64];
  __shared__ alignas(16) float Dv[256];
  __shared__ int wsum[4];
  __shared__ int jbS[80];
  __shared__ int nS;
  __shared__ alignas(16) unsigned char pnB[80*256];   // raw pair rows f16, swz (slot&7)<<4
  __shared__ alignas(16) unsigned char ndB[80*64];    // node_j f16, swz (slot&3)<<4
  __shared__ alignas(16) unsigned char eB [80*64];
  __shared__ alignas(16) unsigned char aB [80*64];
  __shared__ float rsS[80], rmS[80];
  __shared__ float geoS[80][4];
  __shared__ float xjS[80][9];
  __shared__ float cS[80*12];
  __shared__ float pstS[NW][16];
  __shared__ float pofS[NW][9];

  const int item = blockIdx.x;
  const int b = item >> 8;
  const int i = item & 255;

  // ---- P0: top-k mask, in-LDS jlist (threads 0..255) ----
  if (tid<80) jbS[tid] = (b<<8);           // pad (j=0)
  if (tid<16) m0bS[tid] = m0bG[item*16+tid];
  const bool act = tid < 256;
  const int j = tid;
  float D = 0.f;
  const float cax = xyz[(item*3+1)*3+0];
  const float cay = xyz[(item*3+1)*3+1];
  const float caz = xyz[(item*3+1)*3+2];
  if (act){
    const int jb = (b<<8)+j;
    float dx = xyz[(jb*3+1)*3+0]-cax;
    float dy = xyz[(jb*3+1)*3+1]-cay;
    float dz = xyz[(jb*3+1)*3+2]-caz;
    D = sqrtf(dx*dx+dy*dy+dz*dz) + (i==j ? 999.9f : 0.f);
  }
  __syncthreads();
  if (act) Dv[j] = D;
  __syncthreads();
  bool m = false;
  if (act){
    int rank = 0;
    for (int j2=0;j2<256;j2+=4){
      const float4 dv = *(const float4*)&Dv[j2];
      rank += (dv.x < D || (dv.x == D && (j2+0) < j)) ? 1 : 0;
      rank += (dv.y < D || (dv.y == D && (j2+1) < j)) ? 1 : 0;
      rank += (dv.z < D || (dv.z == D && (j2+2) < j)) ? 1 : 0;
      rank += (dv.w < D || (dv.w == D && (j2+3) < j)) ? 1 : 0;
    }
    int K = topk[0];
    if (K<=0 || K>256){
      float f = ((const float*)topk)[0];
      K = (f>=1.f && f<=256.f) ? (int)f : 64;
    }
    const int sep = abs(idxp[(b<<8)+j] - idxp[item]);
    m = (rank < K) || (i!=j && sep < KMINC);
  }
  int pre = 0;
  if (act){
    unsigned long long bal = __ballot(m);
    const int l6 = j & 63, wv = j >> 6;
    pre = __popcll(bal & ((1ull<<l6)-1ull));
    if (l6==0) wsum[wv] = __popcll(bal);
  }
  __syncthreads();
  if (act){
    const int wv = j >> 6;
    int off = 0;
    for (int w2=0;w2<wv;w2++) off += wsum[w2];
    if (m && off+pre < 80) jbS[off+pre] = (b<<8)+j;
    if (j==0) nS = wsum[0]+wsum[1]+wsum[2]+wsum[3];
  }
  __syncthreads();
  const int n = min(nS, 80);

  // ---- P1: issue all pair-row gathers upfront (registers) ----
  float4 pv[8];
  #pragma unroll
  for (int it=0; it<8; ++it){
    const int slot = 16*w + 2*it + h;
    const int jj = jbS[slot] & 255;
    pv[it] = *(const float4*)&pair[(((long)item*256 + jj)*128) + l32*4];
  }

  // ---- P2: weight fold into LDS (executes under the gather latency) ----
  for (int i2=tid;i2<2048;i2+=320){
    int col=i2>>6, wd=i2&63, mm=wd^((col&7)<<2), k0=2*mm;
    ((unsigned*)GwB)[i2] = h2bits(mk2(g_pair[k0]*We[k0*32+col], g_pair[k0+1]*We[(k0+1)*32+col]));
  }
  for (int i2=tid;i2<512;i2+=320){
    int col=i2>>4, wd=i2&15, mm=wd^((col&3)<<2), k0=2*mm;
    ((unsigned*)GwaB)[i2] = h2bits(mk2(g_edge[k0]*Wa[k0*32+col], g_edge[k0+1]*Wa[(k0+1)*32+col]));
  }
  if (tid<256){
    int col=tid>>4, wd=tid&15, mm=wd^((col&3)<<2), k0=2*mm;
    ((unsigned*)W0aB)[tid] = h2bits(mk2(W0[k0*16+col], W0[(k0+1)*16+col]));
    ((unsigned*)W0cB)[tid] = h2bits(mk2(W0[(64+k0)*16+col], W0[(65+k0)*16+col]));
    float lo = (col<3)? Wc1[k0*3+col] : (col<12? Wc2[k0*9+(col-3)] : 0.f);
    float hi = (col<3)? Wc1[(k0+1)*3+col] : (col<12? Wc2[(k0+1)*9+(col-3)] : 0.f);
    ((unsigned*)WcB)[tid] = h2bits(mk2(lo,hi));
  }
  if (tid<32) waDS[tid] = Wa[32*32+tid];
  {
    // gw/bw partials: wave w sums k in [26w, min(26w+26,128)); lane half selects g/b
    const int ks = w*26, ke = min(ks+26,128);
    const float* gsel = (L>>5) ? b_pair : g_pair;
    float acc = 0.f;
    for (int k=ks;k<ke;k++) acc += gsel[k]*We[k*32+(L&31)];
    wfS[w][L] = acc;
    if (w==0){
      const float* gsel2 = (L>>5) ? b_edge : g_edge;
      float acc2 = 0.f;
      for (int k=0;k<32;k++) acc2 += gsel2[k]*Wa[k*32+(L&31)];
      wfS[5][L] = acc2;
    }
  }

  // ---- P3: stage pair rows from regs + LN1 stats + node/xyz staging (wave-local) ----
  #pragma unroll
  for (int it=0; it<8; ++it){
    const int slot = 16*w + 2*it + h;
    const int jb = jbS[slot];
    const float4 pv4 = pv[it];
    const float nv = node[jb*32 + l32];
    if (l32<9) xjS[slot][l32] = xyz[(size_t)jb*9 + l32];
    float sm  = pv4.x+pv4.y+pv4.z+pv4.w;
    float sm2 = pv4.x*pv4.x+pv4.y*pv4.y+pv4.z*pv4.z+pv4.w*pv4.w;
    #pragma unroll
    for (int mm=1;mm<32;mm<<=1){ sm += __shfl_xor(sm,mm,64); sm2 += __shfl_xor(sm2,mm,64); }
    const float mu = sm*(1.f/128.f);
    const float var = sm2*(1.f/128.f)-mu*mu;
    const float rs = rsqrtf(var+EPSLN);
    h4 o; o[0]=(_Float16)pv4.x; o[1]=(_Float16)pv4.y; o[2]=(_Float16)pv4.z; o[3]=(_Float16)pv4.w;
    *(h4*)&pnB[slot*256 + ((l32*8) ^ ((slot&7)<<4))] = o;
    *(_Float16*)&ndB[slot*64 + ((l32*2) ^ ((slot&3)<<4))] = (_Float16)nv;
    if (l32==0){
      rsS[slot]=rs; rmS[slot]=rs*mu;
      float jx = xyz[(size_t)jb*9+3]-cax;
      float jy = xyz[(size_t)jb*9+4]-cay;
      float jz = xyz[(size_t)jb*9+5]-caz;
      geoS[slot][0]=jx; geoS[slot][1]=jy; geoS[slot][2]=jz;
      geoS[slot][3]=sqrtf(jx*jx+jy*jy+jz*jz);
    }
  }
  __syncthreads();
  // combine fold partials
  if (tid<32){
    float g=0.f, bb=0.f;
    #pragma unroll
    for (int k=0;k<5;k++){ g += wfS[k][tid]; bb += wfS[k][32+tid]; }
    gwS[tid]=g; bwS[tid]=bb + be[tid];
    gwaS[tid]=wfS[5][tid]; bwaS[tid]=wfS[5][32+tid] + ba[tid];
  }
  __syncthreads();

  const int sA = 16*w + cl;           // A-frag row-slot for this lane

  // ---- GEMM1: E = P @ Gw  (K=128 -> 4 steps, N=32 -> 2 tiles) ----
  f32x4 accE0 = {0.f,0.f,0.f,0.f}, accE1 = {0.f,0.f,0.f,0.f};
  #pragma unroll
  for (int s=0;s<4;++s){
    const h8 af = asH8(*(const uint4*)&pnB[sA*256 + ((s*64 + q*16) ^ ((sA&7)<<4))]);
    const h8 b0f = asH8(*(const uint4*)&GwB[cl*256 + ((s*64 + q*16) ^ ((cl&7)<<4))]);
    const h8 b1f = asH8(*(const uint4*)&GwB[(16+cl)*256 + ((s*64 + q*16) ^ (((16+cl)&7)<<4))]);
    accE0 = __builtin_amdgcn_mfma_f32_16x16x32_f16(af, b0f, accE0, 0,0,0);
    accE1 = __builtin_amdgcn_mfma_f32_16x16x32_f16(af, b1f, accE1, 0,0,0);
  }

  // ---- LN1 fold -> E raw; LN2 stats ----
  float mu2[4], rs2v[4];
  #pragma unroll
  for (int reg=0;reg<4;++reg){
    const int sr = 16*w + q*4 + reg;
    const float rs1 = rsS[sr], rm1 = rmS[sr];
    const float E0 = rs1*accE0[reg] - rm1*gwS[cl]    + bwS[cl];
    const float E1 = rs1*accE1[reg] - rm1*gwS[16+cl] + bwS[16+cl];
    float s1 = E0+E1, s2 = E0*E0+E1*E1;
    #pragma unroll
    for (int mm=1;mm<16;mm<<=1){ s1 += __shfl_xor(s1,mm,64); s2 += __shfl_xor(s2,mm,64); }
    const float mu = s1*(1.f/32.f);
    const float var = s2*(1.f/32.f)-mu*mu;
    rs2v[reg] = rsqrtf(var+EPSLN);
    mu2[reg]  = mu;
    *(_Float16*)&eB[sr*64 + ((2*cl) ^ ((sr&3)<<4))]      = (_Float16)E0;
    *(_Float16*)&eB[sr*64 + ((2*(16+cl)) ^ ((sr&3)<<4))] = (_Float16)E1;
  }

  // ---- GEMM2: Eraw @ Gwa + fold2 + relu -> aB ----
  {
    const h8 eaf = asH8(*(const uint4*)&eB[sA*64 + ((q*16) ^ ((sA&3)<<4))]);
    const h8 gb0 = asH8(*(const uint4*)&GwaB[cl*64 + ((q*16) ^ ((cl&3)<<4))]);
    const h8 gb1 = asH8(*(const uint4*)&GwaB[(16+cl)*64 + ((q*16) ^ (((16+cl)&3)<<4))]);
    f32x4 z = {0.f,0.f,0.f,0.f};
    f32x4 accA0 = __builtin_amdgcn_mfma_f32_16x16x32_f16(eaf, gb0, z, 0,0,0);
    f32x4 accA1 = __builtin_amdgcn_mfma_f32_16x16x32_f16(eaf, gb1, z, 0,0,0);
    #pragma unroll
    for (int reg=0;reg<4;++reg){
      const int sr = 16*w + q*4 + reg;
      const float dist = geoS[sr][3];
      const float a0 = fmaxf(rs2v[reg]*accA0[reg] - rs2v[reg]*mu2[reg]*gwaS[cl]
                             + bwaS[cl] + dist*waDS[cl], 0.f);
      const float a1 = fmaxf(rs2v[reg]*accA1[reg] - rs2v[reg]*mu2[reg]*gwaS[16+cl]
                             + bwaS[16+cl] + dist*waDS[16+cl], 0.f);
      *(_Float16*)&aB[sr*64 + ((2*cl) ^ ((sr&3)<<4))]      = (_Float16)a0;
      *(_Float16*)&aB[sr*64 + ((2*(16+cl)) ^ ((sr&3)<<4))] = (_Float16)a1;
    }
  }

  // ---- GEMM3: m0 = relu(a@W0a + nd@W0c + m0b) -> state; GEMM4: c = a@Wc ----
  float stP = 0.f;
  {
    const h8 aaf = asH8(*(const uint4*)&aB[sA*64 + ((q*16) ^ ((sA&3)<<4))]);
    const h8 naf = asH8(*(const uint4*)&ndB[sA*64 + ((q*16) ^ ((sA&3)<<4))]);
    const h8 wa0 = asH8(*(const uint4*)&W0aB[cl*64 + ((q*16) ^ ((cl&3)<<4))]);
    const h8 wc0 = asH8(*(const uint4*)&W0cB[cl*64 + ((q*16) ^ ((cl&3)<<4))]);
    const h8 wcf = asH8(*(const uint4*)&WcB[cl*64 + ((q*16) ^ ((cl&3)<<4))]);
    f32x4 z = {0.f,0.f,0.f,0.f};
    f32x4 accM = __builtin_amdgcn_mfma_f32_16x16x32_f16(naf, wc0, z, 0,0,0);
    accM = __builtin_amdgcn_mfma_f32_16x16x32_f16(aaf, wa0, accM, 0,0,0);
    f32x4 accC = __builtin_amdgcn_mfma_f32_16x16x32_f16(aaf, wcf, z, 0,0,0);
    #pragma unroll
    for (int reg=0;reg<4;++reg){
      const int sr = 16*w + q*4 + reg;
      if (sr < n) stP += fmaxf(accM[reg] + m0bS[cl], 0.f);
      if (cl < 12) cS[sr*12 + cl] = accC[reg];
    }
  }
  stP += __shfl_xor(stP, 16, 64);
  stP += __shfl_xor(stP, 32, 64);
  if (L < 16) pstS[w][L] = stP;

  // ---- offsets: each half processes its 8 slots on lanes l32<9 ----
  float ofP = 0.f;
  if (l32 < 9){
    const int o = l32/3, x = l32 - o*3;
    #pragma unroll
    for (int jc=0;jc<8;++jc){
      const int slot = 16*w + h*8 + jc;
      if (slot < n){
        const float dj = geoS[slot][3];
        const float dh = geoS[slot][x]/(dj+1e-8f);
        const float* cr = &cS[slot*12];
        float val = cr[o]*dh;
        const float caxj = xjS[slot][3+x];
        #pragma unroll
        for (int c2=0;c2<3;c2++) val += cr[3+o*3+c2]*(xjS[slot][c2*3+x]-caxj);
        ofP += val;
      }
    }
  }
  ofP += __shfl_xor(ofP, 32, 64);
  if (L < 9) pofS[w][L] = ofP;
  __syncthreads();

  // ---- in-block finisher (wave 0, fixed order -> deterministic) ----
  if (tid < 64){
    const float invd = 1.f/fmaxf((float)n,1.f);
    float sst=0.f, sof=0.f;
    #pragma unroll
    for (int k2=0;k2<NW;k2++){
      if (L<16) sst += pstS[k2][L];
      if (L<9)  sof += pofS[k2][L];
    }
    if (L<16) out[4608 + item*16 + L] = sst*invd;        // state
    const float off = sof*invd;
    const int x = L - (L/3)*3;
    const float offca = __shfl(off, 3+x, 64);            // off[3+x]
    if (L<9){
      const float cac = xyz[(item*3+1)*3 + x];
      const float CA = cac + offca;
      const int o = L/3;
      out[item*9 + L] = (o==1)? CA : (CA + off);         // xyz_new
    }
  }
}

extern "C" void kernel_launch(void* const* d_in, const int* in_sizes, int n_in,
                              void* d_out, int out_size, void* d_ws, size_t ws_size,
                              hipStream_t stream)
{
  const float* msa     = (const float*)d_in[0];
  const float* pair    = (const float*)d_in[1];
  const float* xyz     = (const float*)d_in[2];
  const float* seq1hot = (const float*)d_in[3];
  const float* g_msa   = (const float*)d_in[4];
  const float* b_msa   = (const float*)d_in[5];
  const float* g_pair  = (const float*)d_in[6];
  const float* b_pair  = (const float*)d_in[7];
  const float* Wq      = (const float*)d_in[8];
  const float* bq      = (const float*)d_in[9];
  const float* Wk      = (const float*)d_in[10];
  const float* bk      = (const float*)d_in[11];
  const float* Wx      = (const float*)d_in[12];
  const float* bx      = (const float*)d_in[13];
  const float* g_node  = (const float*)d_in[14];
  const float* b_node  = (const float*)d_in[15];
  const float* We      = (const float*)d_in[16];
  const float* be      = (const float*)d_in[17];
  const float* g_edge  = (const float*)d_in[18];
  const float* b_edge  = (const float*)d_in[19];
  const float* Wa      = (const float*)d_in[20];
  const float* ba      = (const float*)d_in[21];
  const float* W0      = (const float*)d_in[22];
  const float* b0      = (const float*)d_in[23];
  const float* Wc1     = (const float*)d_in[24];
  const float* Wc2     = (const float*)d_in[25];
  const int*   idx     = (const int*)d_in[26];
  const int*   topkp   = (const int*)d_in[27];
  float* out = (float*)d_out;

  float* wsf  = (float*)d_ws;
  float* node = wsf + WS_NODE;
  float* m0bG = wsf + WS_M0B;

  k_node<<<512, 512, 0, stream>>>(msa, seq1hot, g_msa, b_msa, Wq, bq, Wk, bk,
                                  Wx, bx, g_node, b_node, W0, b0, node, m0bG);
  k_rest<<<512, 320, 0, stream>>>(pair, xyz, idx, topkp, g_pair, b_pair,
                                  We, be, g_edge, b_edge, Wa, ba, W0, b0,
                                  Wc1, Wc2, node, m0bG, out);
}